// Round 2
// baseline (230.514 us; speedup 1.0000x reference)
//
#include <hip/hip_runtime.h>
#include <hip/hip_fp16.h>

// out = sa*sb * (x @ q_b) @ q_a^T + bias
// GEMM1: t[8192][512] = x @ q_b      (fp16 MFMA, fp32 acc, t fp16)
// GEMM2: out[8192][4096] = t @ q_a^T (fp16 MFMA, scale+bias epilogue)
// Both GEMMs: 2-phase double-buffered pipeline (stage k+1 before compute k),
// XOR slot-swizzled LDS (source-side permutation for global_load_lds, rule 21).

#define M_TOT 8192
#define N_OUT 4096
#define K_IN  4096
#define RANK  512

typedef _Float16 f16x8 __attribute__((ext_vector_type(8)));
typedef float f32x4 __attribute__((ext_vector_type(4)));

__device__ __forceinline__ void gload_lds16(const void* g, void* l) {
  __builtin_amdgcn_global_load_lds(
      (const __attribute__((address_space(1))) unsigned int*)g,
      (__attribute__((address_space(3))) unsigned int*)l, 16, 0, 0);
}

// ---- convert q_a int32 -> fp16, same [OUT][RANK] layout ----
__global__ void k_cvt_qa(const int4* __restrict__ q, ushort4* __restrict__ o, int n4) {
  int i = blockIdx.x * blockDim.x + threadIdx.x;
  if (i >= n4) return;
  int4 v = q[i];
  ushort4 r;
  r.x = __half_as_ushort(__float2half_rn((float)v.x));
  r.y = __half_as_ushort(__float2half_rn((float)v.y));
  r.z = __half_as_ushort(__float2half_rn((float)v.z));
  r.w = __half_as_ushort(__float2half_rn((float)v.w));
  o[i] = r;
}

// ---- transpose q_b [K_IN][RANK] i32 -> qbt [RANK][K_IN] fp16 ----
__global__ void k_transpose_qb(const int* __restrict__ qb, __half* __restrict__ qbt) {
  __shared__ __half tile[32][33];
  int tx = threadIdx.x & 31, ty = threadIdx.x >> 5;
  int k0 = blockIdx.x * 32, r0 = blockIdx.y * 32;
#pragma unroll
  for (int j = 0; j < 4; ++j)
    tile[ty + j * 8][tx] = __float2half_rn((float)qb[(size_t)(k0 + ty + j * 8) * RANK + r0 + tx]);
  __syncthreads();
#pragma unroll
  for (int j = 0; j < 4; ++j)
    qbt[(size_t)(r0 + ty + j * 8) * K_IN + k0 + tx] = tile[tx][ty + j * 8];
}

// ---- GEMM1: t = X @ qbt^T (M=8192, N=512, K=4096), BM=128 BN=64 BK=64 ----
// 4 waves (2m x 2n), wave tile 64x32, acc[4][2]; A reg-staged fp32->fp16,
// B via global_load_lds with source-side swizzle. LDS dbuf 2x24KB.
// slot swizzle: phys = row*8 + (s ^ (row&7)), 16B slots, 8 slots/row.
__global__ __launch_bounds__(256, 2) void k_gemm1(
    const float* __restrict__ X, const __half* __restrict__ Bt,
    __half* __restrict__ T) {
  __shared__ __align__(16) uint4 lds[2][1536];  // [0,1024)=A, [1024,1536)=B
  const int tid = threadIdx.x;
  const int lane = tid & 63, wid = tid >> 6, wm = wid & 1, wn = wid >> 1;
  const int m0 = blockIdx.x * 128, n0 = blockIdx.y * 64;
  const int fr = lane & 15, fq = lane >> 4;

  f32x4 acc[4][2] = {};

  // A staging: thread t -> row ar=t>>1, slots ah..ah+3 (ah = (t&1)*4)
  const int ar = tid >> 1, ah = (tid & 1) * 4;
  const float* xbase = X + (size_t)(m0 + ar) * K_IN;
  float4 areg[8];

  auto stageB = [&](int k0, int buf) {
#pragma unroll
    for (int c = 0; c < 2; ++c) {
      int d = tid + 256 * c;                // linear dest slot
      int r = d >> 3, sp = d & 7, s = sp ^ (r & 7);  // swizzled source col
      gload_lds16(Bt + (size_t)(n0 + r) * K_IN + k0 + s * 8, &lds[buf][1024 + d]);
    }
  };
  auto loadA = [&](int k0) {
#pragma unroll
    for (int s = 0; s < 4; ++s) {
      areg[2 * s]     = *(const float4*)(xbase + k0 + (ah + s) * 8);
      areg[2 * s + 1] = *(const float4*)(xbase + k0 + (ah + s) * 8 + 4);
    }
  };
  auto writeA = [&](int buf) {
#pragma unroll
    for (int s = 0; s < 4; ++s) {
      union { __half2 h[4]; uint4 u; } p;
      p.h[0] = __floats2half2_rn(areg[2 * s].x, areg[2 * s].y);
      p.h[1] = __floats2half2_rn(areg[2 * s].z, areg[2 * s].w);
      p.h[2] = __floats2half2_rn(areg[2 * s + 1].x, areg[2 * s + 1].y);
      p.h[3] = __floats2half2_rn(areg[2 * s + 1].z, areg[2 * s + 1].w);
      int ss = ah + s;
      lds[buf][ar * 8 + (ss ^ (ar & 7))] = p.u;
    }
  };

  // prologue: stage tile 0 into buf 0
  stageB(0, 0);
  loadA(0);
  writeA(0);
  __syncthreads();

  const int NT = K_IN / 64;
  int cur = 0;
  for (int kt = 0; kt < NT; ++kt) {
    const int nxt = cur ^ 1;
    if (kt + 1 < NT) {            // issue next-tile loads BEFORE compute
      stageB((kt + 1) * 64, nxt);
      loadA((kt + 1) * 64);
    }
    f16x8 a[4][2], b[2][2];
#pragma unroll
    for (int kk = 0; kk < 2; ++kk) {
      int s = kk * 4 + fq;
#pragma unroll
      for (int mi = 0; mi < 4; ++mi) {
        int r = wm * 64 + mi * 16 + fr;
        a[mi][kk] = *(const f16x8*)&lds[cur][r * 8 + (s ^ (r & 7))];
      }
#pragma unroll
      for (int ni = 0; ni < 2; ++ni) {
        int n = wn * 32 + ni * 16 + fr;
        b[ni][kk] = *(const f16x8*)&lds[cur][1024 + n * 8 + (s ^ (n & 7))];
      }
    }
#pragma unroll
    for (int kk = 0; kk < 2; ++kk)
#pragma unroll
      for (int mi = 0; mi < 4; ++mi)
#pragma unroll
        for (int ni = 0; ni < 2; ++ni)
          acc[mi][ni] = __builtin_amdgcn_mfma_f32_16x16x32_f16(a[mi][kk], b[ni][kk], acc[mi][ni], 0, 0, 0);
    if (kt + 1 < NT) writeA(nxt);   // cvt waits the float4s (landed under MFMA)
    __syncthreads();
    cur = nxt;
  }

#pragma unroll
  for (int mi = 0; mi < 4; ++mi)
#pragma unroll
    for (int ni = 0; ni < 2; ++ni) {
      int col = n0 + wn * 32 + ni * 16 + fr;
      int rbase = m0 + wm * 64 + mi * 16 + fq * 4;
#pragma unroll
      for (int j = 0; j < 4; ++j)
        T[(size_t)(rbase + j) * RANK + col] = __float2half_rn(acc[mi][ni][j]);
    }
}

// ---- GEMM2: out = t @ qa^T * scale + bias (M=8192, N=4096, K=512) ----
// 128x128x32, 2-phase dbuf, both operands global_load_lds w/ source swizzle.
// rows are 4 slots: phys = row*4 + (s ^ (row&3)); residual 4-way conflict.
__global__ __launch_bounds__(256, 2) void k_gemm2(
    const __half* __restrict__ T, const __half* __restrict__ QA,
    const float* __restrict__ sa, const float* __restrict__ sb,
    const float* __restrict__ bias, float* __restrict__ Out) {
  __shared__ __align__(16) uint4 lds[2][1024];  // [0,512)=A, [512,1024)=B
  const int tid = threadIdx.x;
  const int lane = tid & 63, wid = tid >> 6, wm = wid & 1, wn = wid >> 1;
  const int m0 = blockIdx.x * 128, n0 = blockIdx.y * 128;
  const int fr = lane & 15, fq = lane >> 4;

  f32x4 acc[4][4] = {};

  auto stage = [&](int kt, int buf) {
#pragma unroll
    for (int c = 0; c < 2; ++c) {
      int d = tid + 256 * c;
      int r = d >> 2, sp = d & 3, s = sp ^ (r & 3);
      gload_lds16(T + (size_t)(m0 + r) * RANK + kt * 32 + s * 8, &lds[buf][d]);
    }
#pragma unroll
    for (int c = 0; c < 2; ++c) {
      int d = tid + 256 * c;
      int r = d >> 2, sp = d & 3, s = sp ^ (r & 3);
      gload_lds16(QA + (size_t)(n0 + r) * RANK + kt * 32 + s * 8, &lds[buf][512 + d]);
    }
  };

  stage(0, 0);
  __syncthreads();

  const int NT = RANK / 32;
  int cur = 0;
  for (int kt = 0; kt < NT; ++kt) {
    const int nxt = cur ^ 1;
    if (kt + 1 < NT) stage(kt + 1, nxt);
    f16x8 a[4], b[4];
#pragma unroll
    for (int mi = 0; mi < 4; ++mi) {
      int r = wm * 64 + mi * 16 + fr;
      a[mi] = *(const f16x8*)&lds[cur][r * 4 + (fq ^ (r & 3))];
    }
#pragma unroll
    for (int ni = 0; ni < 4; ++ni) {
      int n = wn * 64 + ni * 16 + fr;
      b[ni] = *(const f16x8*)&lds[cur][512 + n * 4 + (fq ^ (n & 3))];
    }
#pragma unroll
    for (int mi = 0; mi < 4; ++mi)
#pragma unroll
      for (int ni = 0; ni < 4; ++ni)
        acc[mi][ni] = __builtin_amdgcn_mfma_f32_16x16x32_f16(a[mi], b[ni], acc[mi][ni], 0, 0, 0);
    __syncthreads();
    cur = nxt;
  }

  const float scale = sa[0] * sb[0];
#pragma unroll
  for (int mi = 0; mi < 4; ++mi)
#pragma unroll
    for (int ni = 0; ni < 4; ++ni) {
      int col = n0 + wn * 64 + ni * 16 + fr;
      float bv = bias[col];
      int rbase = m0 + wm * 64 + mi * 16 + fq * 4;
#pragma unroll
      for (int j = 0; j < 4; ++j)
        Out[(size_t)(rbase + j) * N_OUT + col] = acc[mi][ni][j] * scale + bv;
    }
}

extern "C" void kernel_launch(void* const* d_in, const int* in_sizes, int n_in,
                              void* d_out, int out_size, void* d_ws, size_t ws_size,
                              hipStream_t stream) {
  const float* x    = (const float*)d_in[0];
  const int*   qa   = (const int*)d_in[1];
  const int*   qb   = (const int*)d_in[2];
  const float* sa   = (const float*)d_in[3];
  const float* sb   = (const float*)d_in[4];
  const float* bias = (const float*)d_in[5];
  float* out = (float*)d_out;

  char* ws = (char*)d_ws;
  __half* qa_h = (__half*)ws;                 // 4 MB
  __half* qbt  = (__half*)(ws + (4u << 20));  // 4 MB
  __half* t    = (__half*)(ws + (8u << 20));  // 8 MB

  k_cvt_qa<<<2048, 256, 0, stream>>>((const int4*)qa, (ushort4*)qa_h, (N_OUT * RANK) / 4);
  dim3 tg(K_IN / 32, RANK / 32);
  k_transpose_qb<<<tg, 256, 0, stream>>>(qb, qbt);
  dim3 g1(M_TOT / 128, RANK / 64);
  k_gemm1<<<g1, 256, 0, stream>>>(x, qbt, t);
  dim3 g2(M_TOT / 128, N_OUT / 128);
  k_gemm2<<<g2, 256, 0, stream>>>(t, qa_h, sa, sb, bias, out);
}

// Round 3
// 172.370 us; speedup vs baseline: 1.3373x; 1.3373x over previous
//
#include <hip/hip_runtime.h>
#include <hip/hip_fp16.h>

// out = sa*sb * (x @ q_b) @ q_a^T + bias
// GEMM1: t[8192][512] = x @ q_b      (fp16 MFMA, fp32 acc, t fp16)
// GEMM2: out[8192][4096] = t @ q_a^T (fp16 MFMA, scale+bias epilogue)
// Round 3: small tiles + high occupancy (4 blocks/CU), simple 2-barrier
// structure (round-1 skeleton), zero-conflict XOR slot swizzle kept.

#define M_TOT 8192
#define N_OUT 4096
#define K_IN  4096
#define RANK  512

typedef _Float16 f16x8 __attribute__((ext_vector_type(8)));
typedef float f32x4 __attribute__((ext_vector_type(4)));

__device__ __forceinline__ void gload_lds16(const void* g, void* l) {
  __builtin_amdgcn_global_load_lds(
      (const __attribute__((address_space(1))) unsigned int*)g,
      (__attribute__((address_space(3))) unsigned int*)l, 16, 0, 0);
}

// ---- convert q_a int32 -> fp16, same [OUT][RANK] layout ----
__global__ void k_cvt_qa(const int4* __restrict__ q, ushort4* __restrict__ o, int n4) {
  int i = blockIdx.x * blockDim.x + threadIdx.x;
  if (i >= n4) return;
  int4 v = q[i];
  ushort4 r;
  r.x = __half_as_ushort(__float2half_rn((float)v.x));
  r.y = __half_as_ushort(__float2half_rn((float)v.y));
  r.z = __half_as_ushort(__float2half_rn((float)v.z));
  r.w = __half_as_ushort(__float2half_rn((float)v.w));
  o[i] = r;
}

// ---- transpose q_b [K_IN][RANK] i32 -> qbt [RANK][K_IN] fp16 ----
__global__ void k_transpose_qb(const int* __restrict__ qb, __half* __restrict__ qbt) {
  __shared__ __half tile[32][33];
  int tx = threadIdx.x & 31, ty = threadIdx.x >> 5;
  int k0 = blockIdx.x * 32, r0 = blockIdx.y * 32;
#pragma unroll
  for (int j = 0; j < 4; ++j)
    tile[ty + j * 8][tx] = __float2half_rn((float)qb[(size_t)(k0 + ty + j * 8) * RANK + r0 + tx]);
  __syncthreads();
#pragma unroll
  for (int j = 0; j < 4; ++j)
    qbt[(size_t)(r0 + ty + j * 8) * K_IN + k0 + tx] = tile[tx][ty + j * 8];
}

// ---- GEMM1: t = X @ qbt^T (M=8192, N=512, K=4096) ----
// BM=64 BN=64 BK=64, 256 thr = 4 waves (2m x 2n), wave tile 32x32, acc[2][2]
// grid 128x8 = 1024 blocks -> 4 blocks/CU. LDS 16 KB single-buffer.
// slot swizzle: phys = row*8 + (s ^ (row&7)); 16B slots, 8 slots/row.
__global__ __launch_bounds__(256, 4) void k_gemm1(
    const float* __restrict__ X, const __half* __restrict__ Bt,
    __half* __restrict__ T) {
  __shared__ __align__(16) uint4 lds[1024];  // [0,512)=A 64x8, [512,1024)=B 64x8
  const int tid = threadIdx.x;
  const int lane = tid & 63, wid = tid >> 6, wm = wid & 1, wn = wid >> 1;
  const int m0 = blockIdx.x * 64, n0 = blockIdx.y * 64;
  const int fr = lane & 15, fq = lane >> 4;

  f32x4 acc[2][2] = {};

  // A stage: thread t -> row r=t>>2, quarter q=t&3 (16 floats -> 2 slots)
  const int ar = tid >> 2, aq = tid & 3;
  const float* xbase = X + (size_t)(m0 + ar) * K_IN + aq * 16;
  // B stage: 2x gload_lds16; linear dest d, swizzled source col
  const int bd0 = tid, bd1 = tid + 256;
  const __half* bsrc0 = Bt + (size_t)(n0 + (bd0 >> 3)) * K_IN + ((bd0 & 7) ^ ((bd0 >> 3) & 7)) * 8;
  const __half* bsrc1 = Bt + (size_t)(n0 + (bd1 >> 3)) * K_IN + ((bd1 & 7) ^ ((bd1 >> 3) & 7)) * 8;

  for (int k0 = 0; k0 < K_IN; k0 += 64) {
    gload_lds16(bsrc0 + k0, &lds[512 + bd0]);
    gload_lds16(bsrc1 + k0, &lds[512 + bd1]);
    float4 v0 = *(const float4*)(xbase + k0);
    float4 v1 = *(const float4*)(xbase + k0 + 4);
    float4 v2 = *(const float4*)(xbase + k0 + 8);
    float4 v3 = *(const float4*)(xbase + k0 + 12);
    union { __half2 h[4]; uint4 u; } p0, p1;
    p0.h[0] = __floats2half2_rn(v0.x, v0.y);
    p0.h[1] = __floats2half2_rn(v0.z, v0.w);
    p0.h[2] = __floats2half2_rn(v1.x, v1.y);
    p0.h[3] = __floats2half2_rn(v1.z, v1.w);
    p1.h[0] = __floats2half2_rn(v2.x, v2.y);
    p1.h[1] = __floats2half2_rn(v2.z, v2.w);
    p1.h[2] = __floats2half2_rn(v3.x, v3.y);
    p1.h[3] = __floats2half2_rn(v3.z, v3.w);
    lds[ar * 8 + ((2 * aq) ^ (ar & 7))] = p0.u;
    lds[ar * 8 + ((2 * aq + 1) ^ (ar & 7))] = p1.u;
    __syncthreads();
    f16x8 a[2][2], b[2][2];
#pragma unroll
    for (int kk = 0; kk < 2; ++kk) {
      int s = kk * 4 + fq;
#pragma unroll
      for (int mi = 0; mi < 2; ++mi) {
        int r = wm * 32 + mi * 16 + fr;
        a[mi][kk] = *(const f16x8*)&lds[r * 8 + (s ^ (r & 7))];
      }
#pragma unroll
      for (int ni = 0; ni < 2; ++ni) {
        int n = wn * 32 + ni * 16 + fr;
        b[ni][kk] = *(const f16x8*)&lds[512 + n * 8 + (s ^ (n & 7))];
      }
    }
#pragma unroll
    for (int kk = 0; kk < 2; ++kk)
#pragma unroll
      for (int mi = 0; mi < 2; ++mi)
#pragma unroll
        for (int ni = 0; ni < 2; ++ni)
          acc[mi][ni] = __builtin_amdgcn_mfma_f32_16x16x32_f16(a[mi][kk], b[ni][kk], acc[mi][ni], 0, 0, 0);
    __syncthreads();
  }

#pragma unroll
  for (int mi = 0; mi < 2; ++mi)
#pragma unroll
    for (int ni = 0; ni < 2; ++ni) {
      int col = n0 + wn * 32 + ni * 16 + fr;
      int rbase = m0 + wm * 32 + mi * 16 + fq * 4;
#pragma unroll
      for (int j = 0; j < 4; ++j)
        T[(size_t)(rbase + j) * RANK + col] = __float2half_rn(acc[mi][ni][j]);
    }
}

// ---- GEMM2: out = t @ qa^T * scale + bias (M=8192, N=4096, K=512) ----
// BM=128 BN=64 BK=64, 256 thr = 4 waves (2m x 2n), wave tile 64x32, acc[4][2]
// grid 64x64 = 4096 blocks. LDS 24 KB single-buffer, both operands gload_lds.
__global__ __launch_bounds__(256, 4) void k_gemm2(
    const __half* __restrict__ T, const __half* __restrict__ QA,
    const float* __restrict__ sa, const float* __restrict__ sb,
    const float* __restrict__ bias, float* __restrict__ Out) {
  __shared__ __align__(16) uint4 lds[1536];  // [0,1024)=A 128x8, [1024,1536)=B 64x8
  const int tid = threadIdx.x;
  const int lane = tid & 63, wid = tid >> 6, wm = wid & 1, wn = wid >> 1;
  const int m0 = blockIdx.x * 128, n0 = blockIdx.y * 64;
  const int fr = lane & 15, fq = lane >> 4;

  f32x4 acc[4][2] = {};

  for (int kt = 0; kt < RANK / 64; ++kt) {
#pragma unroll
    for (int c = 0; c < 4; ++c) {
      int d = tid + 256 * c;
      int r = d >> 3, s = (d & 7) ^ (r & 7);
      gload_lds16(T + (size_t)(m0 + r) * RANK + kt * 64 + s * 8, &lds[d]);
    }
#pragma unroll
    for (int c = 0; c < 2; ++c) {
      int d = tid + 256 * c;
      int r = d >> 3, s = (d & 7) ^ (r & 7);
      gload_lds16(QA + (size_t)(n0 + r) * RANK + kt * 64 + s * 8, &lds[1024 + d]);
    }
    __syncthreads();
    f16x8 a[4][2], b[2][2];
#pragma unroll
    for (int kk = 0; kk < 2; ++kk) {
      int s = kk * 4 + fq;
#pragma unroll
      for (int mi = 0; mi < 4; ++mi) {
        int r = wm * 64 + mi * 16 + fr;
        a[mi][kk] = *(const f16x8*)&lds[r * 8 + (s ^ (r & 7))];
      }
#pragma unroll
      for (int ni = 0; ni < 2; ++ni) {
        int n = wn * 32 + ni * 16 + fr;
        b[ni][kk] = *(const f16x8*)&lds[1024 + n * 8 + (s ^ (n & 7))];
      }
    }
#pragma unroll
    for (int kk = 0; kk < 2; ++kk)
#pragma unroll
      for (int mi = 0; mi < 4; ++mi)
#pragma unroll
        for (int ni = 0; ni < 2; ++ni)
          acc[mi][ni] = __builtin_amdgcn_mfma_f32_16x16x32_f16(a[mi][kk], b[ni][kk], acc[mi][ni], 0, 0, 0);
    __syncthreads();
  }

  const float scale = sa[0] * sb[0];
#pragma unroll
  for (int mi = 0; mi < 4; ++mi)
#pragma unroll
    for (int ni = 0; ni < 2; ++ni) {
      int col = n0 + wn * 32 + ni * 16 + fr;
      float bv = bias[col];
      int rbase = m0 + wm * 64 + mi * 16 + fq * 4;
#pragma unroll
      for (int j = 0; j < 4; ++j)
        Out[(size_t)(rbase + j) * N_OUT + col] = acc[mi][ni][j] * scale + bv;
    }
}

extern "C" void kernel_launch(void* const* d_in, const int* in_sizes, int n_in,
                              void* d_out, int out_size, void* d_ws, size_t ws_size,
                              hipStream_t stream) {
  const float* x    = (const float*)d_in[0];
  const int*   qa   = (const int*)d_in[1];
  const int*   qb   = (const int*)d_in[2];
  const float* sa   = (const float*)d_in[3];
  const float* sb   = (const float*)d_in[4];
  const float* bias = (const float*)d_in[5];
  float* out = (float*)d_out;

  char* ws = (char*)d_ws;
  __half* qa_h = (__half*)ws;                 // 4 MB
  __half* qbt  = (__half*)(ws + (4u << 20));  // 4 MB
  __half* t    = (__half*)(ws + (8u << 20));  // 8 MB

  k_cvt_qa<<<2048, 256, 0, stream>>>((const int4*)qa, (ushort4*)qa_h, (N_OUT * RANK) / 4);
  dim3 tg(K_IN / 32, RANK / 32);
  k_transpose_qb<<<tg, 256, 0, stream>>>(qb, qbt);
  dim3 g1(M_TOT / 64, RANK / 64);
  k_gemm1<<<g1, 256, 0, stream>>>(x, qbt, t);
  dim3 g2(M_TOT / 128, N_OUT / 64);
  k_gemm2<<<g2, 256, 0, stream>>>(t, qa_h, sa, sb, bias, out);
}